// Round 1
// baseline (351.012 us; speedup 1.0000x reference)
//
#include <hip/hip_runtime.h>
#include <hip/hip_bf16.h>
#include <math.h>

typedef __hip_bfloat16 bf16;
typedef __bf16 bf16x8 __attribute__((ext_vector_type(8)));
typedef float f32x4 __attribute__((ext_vector_type(4)));

static __device__ __forceinline__ float b2f(bf16 v) { return __bfloat162float(v); }
static __device__ __forceinline__ bf16 f2b(float v) { return __float2bfloat16(v); }

// async global->LDS, 16B per lane; LDS dest = wave-uniform base + lane*16
#define GLOAD16(g, l) __builtin_amdgcn_global_load_lds( \
    (const __attribute__((address_space(1))) void*)(g), \
    (__attribute__((address_space(3))) void*)(l), 16, 0, 0)

// ---------------------------------------------------------------------------
// Generic MFMA GEMM:  D[m][n] = sum_k A[m][k] * Bt[n][k]  (+ bias[m])
// Tile 128(M) x 64(N), BK=32, m97-style staging: linear LDS + global_load_lds.
// 256 thr = 4 waves. M%128==0, N%64==0, K%32==0, K-rows 16B aligned.
// ---------------------------------------------------------------------------
#define TM 128
#define TN 64
#define TK 32

template <typename TOUT>
__global__ __launch_bounds__(256) void gemm_bt(
    const bf16* __restrict__ A, size_t sA,
    const bf16* __restrict__ Bt, size_t sB,
    const float* __restrict__ bias, size_t sBias, int hasBias,
    TOUT* __restrict__ D, size_t sD,
    int M, int N, int Kd, int transStore)
{
    A  += (size_t)blockIdx.z * sA;
    Bt += (size_t)blockIdx.z * sB;
    D  += (size_t)blockIdx.z * sD;
    if (hasBias) bias += (size_t)blockIdx.z * sBias;

    const int m0 = blockIdx.y * TM, n0 = blockIdx.x * TN;
    const int t = threadIdx.x, wv = t >> 6, lane = t & 63;
    const int lr = lane & 15, quad = lane >> 4;

    __shared__ bf16 lA[TM * TK];
    __shared__ bf16 lB[TN * TK];

    f32x4 acc[2][4];
#pragma unroll
    for (int i = 0; i < 2; ++i)
#pragma unroll
        for (int j = 0; j < 4; ++j) acc[i][j] = (f32x4){0.f, 0.f, 0.f, 0.f};

    // staging: wave wv covers rows [wv*16, wv*16+16) (+64 for A's 2nd half)
    const int srow = lane >> 2, scol = (lane & 3) * 8;
    const bf16* as0 = A  + (size_t)(m0 + wv * 16 + srow) * Kd + scol;
    const bf16* bs0 = Bt + (size_t)(n0 + wv * 16 + srow) * Kd + scol;
    bf16* la0 = lA + wv * 512;
    bf16* lb0 = lB + wv * 512;

    for (int k0 = 0; k0 < Kd; k0 += TK) {
        __syncthreads();
        GLOAD16(as0 + k0, la0);
        GLOAD16(as0 + (size_t)64 * Kd + k0, la0 + 2048);
        GLOAD16(bs0 + k0, lb0);
        __syncthreads();

        bf16x8 af0 = *(const bf16x8*)(lA + (wv * 32 + lr) * 32 + quad * 8);
        bf16x8 af1 = *(const bf16x8*)(lA + (wv * 32 + 16 + lr) * 32 + quad * 8);
#pragma unroll
        for (int j = 0; j < 4; ++j) {
            bf16x8 bfj = *(const bf16x8*)(lB + (j * 16 + lr) * 32 + quad * 8);
            acc[0][j] = __builtin_amdgcn_mfma_f32_16x16x32_bf16(af0, bfj, acc[0][j], 0, 0, 0);
            acc[1][j] = __builtin_amdgcn_mfma_f32_16x16x32_bf16(af1, bfj, acc[1][j], 0, 0, 0);
        }
    }

#pragma unroll
    for (int i = 0; i < 2; ++i) {
        const int mb = m0 + wv * 32 + i * 16 + quad * 4;
#pragma unroll
        for (int r = 0; r < 4; ++r) {
            const int mm = mb + r;
            const float bvv = hasBias ? bias[mm] : 0.f;
#pragma unroll
            for (int j = 0; j < 4; ++j) {
                const int nn = n0 + j * 16 + lr;
                const float v = acc[i][j][r] + bvv;
                const size_t o = transStore ? ((size_t)nn * M + mm)
                                            : ((size_t)mm * N + nn);
                if constexpr (__is_same(TOUT, float)) D[o] = v;
                else                                  D[o] = f2b(v);
            }
        }
    }
}

// ---------------------------------------------------------------------------
// x prep: x[b][512][4096] f32 -> xT[b][4096][512] bf16 (transpose+cast),
// fused per-channel partial sums xsump[8][b*512+c] (for the GAP branch).
// Grid (8 n-chunks of 512, 8 c-chunks of 64, 8 batches), 256 thr.
// ---------------------------------------------------------------------------
__global__ __launch_bounds__(256) void k_prep(const float* __restrict__ x,
                                              bf16* __restrict__ xT,
                                              float* __restrict__ xsump)
{
    const int b = blockIdx.z;
    const int c0 = blockIdx.y * 64;
    const int n0 = blockIdx.x * 512;
    const int t = threadIdx.x;
    const int cr = t >> 2;        // 0..63
    const int sub = t & 3;        // 0..3
    __shared__ bf16 tile[64][72];

    const float* xrow = x + ((size_t)b * 512 + c0 + cr) * 4096 + n0 + sub * 16;
    float s = 0.f;

    for (int st = 0; st < 8; ++st) {
        __syncthreads();
        float4 f[4];
#pragma unroll
        for (int q = 0; q < 4; ++q) f[q] = *(const float4*)(xrow + st * 64 + q * 4);
#pragma unroll
        for (int q = 0; q < 4; ++q) {
            s += f[q].x + f[q].y + f[q].z + f[q].w;
            union { bf16 h[4]; uint2 u; } p;
            p.h[0] = f2b(f[q].x); p.h[1] = f2b(f[q].y);
            p.h[2] = f2b(f[q].z); p.h[3] = f2b(f[q].w);
            *(uint2*)&tile[cr][sub * 16 + q * 4] = p.u;
        }
        __syncthreads();
        union { bf16 h[8]; uint4 u; } o0, o1;
#pragma unroll
        for (int i = 0; i < 8; ++i) o0.h[i] = tile[sub * 16 + i][cr];
#pragma unroll
        for (int i = 0; i < 8; ++i) o1.h[i] = tile[sub * 16 + 8 + i][cr];
        bf16* orow = xT + ((size_t)b * 4096 + n0 + st * 64 + cr) * 512 + c0 + sub * 16;
        *(uint4*)(orow)     = o0.u;
        *(uint4*)(orow + 8) = o1.u;
    }
    s += __shfl_down(s, 2);
    s += __shfl_down(s, 1);
    if (sub == 0) xsump[(size_t)blockIdx.x * 4096 + b * 512 + c0 + cr] = s;
}

// ---------------------------------------------------------------------------
// QKV GEMM with modulation folded into weights:
//   q/k/v = (Wg*(1+scale)) @ x + (b + Wg@shift)
// A = wqkv_g [b][768][512] bf16 (scale pre-folded), Bt = xT [b][4096][512].
// m97 structure: 128x128 tile, linear LDS, global_load_lds w=16.
// Grid (6 m-tiles fastest for B-tile L2 reuse, 32 n-tiles, 8 batches).
// q,k natural [b][256][4096]; v transposed [b][4096][256].
// ---------------------------------------------------------------------------
__global__ __launch_bounds__(256) void gemm_qkv2(
    const bf16* __restrict__ Aall, const bf16* __restrict__ xT,
    const float* __restrict__ bias,
    bf16* __restrict__ qb, bf16* __restrict__ kb, bf16* __restrict__ vT)
{
    const int b = blockIdx.z;
    const int mt = blockIdx.x;            // 0..5
    const int n0 = blockIdx.y * 128;
    const bf16* A  = Aall + (size_t)b * 393216 + (size_t)mt * 65536;
    const bf16* Bt = xT + (size_t)b * 2097152;
    bias += b * 768 + mt * 128;

    const int t = threadIdx.x, w = t >> 6, lane = t & 63;
    const int lr = lane & 15, quad = lane >> 4;
    const int wr = w >> 1, wc = w & 1;

    __shared__ bf16 lA[128 * 32];
    __shared__ bf16 lB[128 * 32];

    f32x4 acc[4][4];
#pragma unroll
    for (int i = 0; i < 4; ++i)
#pragma unroll
        for (int j = 0; j < 4; ++j) acc[i][j] = (f32x4){0.f, 0.f, 0.f, 0.f};

    const int srow = lane >> 2, scol = (lane & 3) * 8;
    const bf16* as0 = A  + (size_t)(w * 16 + srow) * 512 + scol;
    const bf16* bs0 = Bt + (size_t)(n0 + w * 16 + srow) * 512 + scol;
    bf16* la0 = lA + w * 512;
    bf16* lb0 = lB + w * 512;

    for (int k0 = 0; k0 < 512; k0 += 32) {
        __syncthreads();
        GLOAD16(as0 + k0, la0);
        GLOAD16(as0 + 32768 + k0, la0 + 2048);   // +64 rows * 512
        GLOAD16(bs0 + k0, lb0);
        GLOAD16(bs0 + 32768 + k0, lb0 + 2048);
        __syncthreads();

        bf16x8 af[4], bfr[4];
#pragma unroll
        for (int i = 0; i < 4; ++i)
            af[i] = *(const bf16x8*)(lA + (wr * 64 + i * 16 + lr) * 32 + quad * 8);
#pragma unroll
        for (int j = 0; j < 4; ++j)
            bfr[j] = *(const bf16x8*)(lB + (wc * 64 + j * 16 + lr) * 32 + quad * 8);
#pragma unroll
        for (int i = 0; i < 4; ++i)
#pragma unroll
            for (int j = 0; j < 4; ++j)
                acc[i][j] = __builtin_amdgcn_mfma_f32_16x16x32_bf16(af[i], bfr[j], acc[i][j], 0, 0, 0);
    }

#pragma unroll
    for (int i = 0; i < 4; ++i) {
        const int mq = wr * 64 + i * 16 + quad * 4;
#pragma unroll
        for (int r = 0; r < 4; ++r) {
            const int ml = mq + r;                 // 0..127 in tile
            const float bvv = bias[ml];
            const int mmg = mt * 128 + ml;         // 0..767
            const int mloc = mmg & 255;
#pragma unroll
            for (int j = 0; j < 4; ++j) {
                const int nn = n0 + wc * 64 + j * 16 + lr;
                const float v = acc[i][j][r] + bvv;
                if (mmg < 256)      qb[(size_t)b * 1048576 + (size_t)mloc * 4096 + nn] = f2b(v);
                else if (mmg < 512) kb[(size_t)b * 1048576 + (size_t)mloc * 4096 + nn] = f2b(v);
                else                vT[(size_t)b * 1048576 + (size_t)nn * 256 + mloc] = f2b(v);
            }
        }
    }
}

// ---------------------------------------------------------------------------
// Split-K S-GEMM: part[s][b][m][n] = sum_{k in chunk s} q[b][m][k]*k[b][n][k]
// 8 splits of 512; m97-style staging.
// ---------------------------------------------------------------------------
__global__ __launch_bounds__(256) void gemm_s_splitk(
    const bf16* __restrict__ qb, const bf16* __restrict__ kb,
    float* __restrict__ part)
{
    const int b = blockIdx.z >> 3, s = blockIdx.z & 7;
    const int m0 = blockIdx.y * TM, n0 = blockIdx.x * TN;
    const bf16* A  = qb + (size_t)b * 1048576;
    const bf16* Bt = kb + (size_t)b * 1048576;

    const int t = threadIdx.x, wv = t >> 6, lane = t & 63;
    const int lr = lane & 15, quad = lane >> 4;

    __shared__ bf16 lA[TM * TK];
    __shared__ bf16 lB[TN * TK];

    f32x4 acc[2][4];
#pragma unroll
    for (int i = 0; i < 2; ++i)
#pragma unroll
        for (int j = 0; j < 4; ++j) acc[i][j] = (f32x4){0.f, 0.f, 0.f, 0.f};

    const int srow = lane >> 2, scol = (lane & 3) * 8;
    const bf16* as0 = A  + (size_t)(m0 + wv * 16 + srow) * 4096 + scol;
    const bf16* bs0 = Bt + (size_t)(n0 + wv * 16 + srow) * 4096 + scol;
    bf16* la0 = lA + wv * 512;
    bf16* lb0 = lB + wv * 512;

    const int kBeg = s * 512, kEnd = kBeg + 512;
    for (int k0 = kBeg; k0 < kEnd; k0 += TK) {
        __syncthreads();
        GLOAD16(as0 + k0, la0);
        GLOAD16(as0 + (size_t)64 * 4096 + k0, la0 + 2048);
        GLOAD16(bs0 + k0, lb0);
        __syncthreads();

        bf16x8 af0 = *(const bf16x8*)(lA + (wv * 32 + lr) * 32 + quad * 8);
        bf16x8 af1 = *(const bf16x8*)(lA + (wv * 32 + 16 + lr) * 32 + quad * 8);
#pragma unroll
        for (int j = 0; j < 4; ++j) {
            bf16x8 bfj = *(const bf16x8*)(lB + (j * 16 + lr) * 32 + quad * 8);
            acc[0][j] = __builtin_amdgcn_mfma_f32_16x16x32_bf16(af0, bfj, acc[0][j], 0, 0, 0);
            acc[1][j] = __builtin_amdgcn_mfma_f32_16x16x32_bf16(af1, bfj, acc[1][j], 0, 0, 0);
        }
    }

    float* dst = part + ((size_t)(s * 8 + b) * 256) * 256;
#pragma unroll
    for (int i = 0; i < 2; ++i) {
        const int mb = m0 + wv * 32 + i * 16 + quad * 4;
#pragma unroll
        for (int r = 0; r < 4; ++r) {
            const int mm = mb + r;
#pragma unroll
            for (int j = 0; j < 4; ++j)
                dst[(size_t)mm * 256 + n0 + j * 16 + lr] = acc[i][j][r];
        }
    }
}

// ---------------------------------------------------------------------------
// Small kernels
// ---------------------------------------------------------------------------

__global__ void k_silu(const float* __restrict__ in, float* __restrict__ out, int n)
{
    int i = blockIdx.x * 256 + threadIdx.x;
    if (i < n) {
        float v = in[i];
        out[i] = v / (1.f + expf(-v));
    }
}

__global__ void k_smallgemm(const float* __restrict__ in, const float* __restrict__ W,
                            const float* __restrict__ bias, float* __restrict__ out,
                            int Mrows, int O, int Kd, int act)
{
    const int gw = (blockIdx.x * 256 + threadIdx.x) >> 6;
    const int lane = threadIdx.x & 63;
    if (gw >= Mrows * O) return;
    const int m = gw / O, o = gw - m * O;
    float s = 0.f;
    for (int k = lane; k < Kd; k += 64)
        s += in[m * Kd + k] * W[(size_t)o * Kd + k];
    for (int off = 32; off; off >>= 1) s += __shfl_down(s, off);
    if (lane == 0) {
        s += bias[o];
        if (act) s = s / (1.f + expf(-s));
        out[m * O + o] = s;
    }
}

// hidden[m][o] = silu(pm @ w_m1^T + b_m1); pm from ss / xsump(sum of 8, /4096) / tp
__global__ void k_mlp1(const float* __restrict__ ss, const float* __restrict__ xsump,
                       const float* __restrict__ tp, const float* __restrict__ w_m1,
                       const float* __restrict__ b_m1, float* __restrict__ hidden)
{
    const int gw = (blockIdx.x * 256 + threadIdx.x) >> 6;
    const int lane = threadIdx.x & 63;
    if (gw >= 8 * 1024) return;
    const int m = gw >> 10, o = gw & 1023;
    float s = 0.f;
    for (int k = lane; k < 1024; k += 64) {
        float pv;
        if (k < 512) {
            float xs = 0.f;
#pragma unroll
            for (int p = 0; p < 8; ++p) xs += xsump[p * 4096 + m * 512 + k];
            pv = (1.f + ss[m * 1024 + k]) * (xs * (1.f / 4096.f))
                 + ss[m * 1024 + 512 + k];
        } else {
            pv = tp[m * 512 + k - 512];
        }
        s += pv * w_m1[(size_t)o * 1024 + k];
    }
    for (int off = 32; off; off >>= 1) s += __shfl_down(s, off);
    if (lane == 0) {
        s += b_m1[o];
        hidden[m * 1024 + o] = s / (1.f + expf(-s));
    }
}

// top-256 set (order-free downstream; rank tie-break by lower index)
__global__ void k_topk(const float* __restrict__ prompt, int* __restrict__ idx)
{
    __shared__ float v[512];
    __shared__ int sel[512];
    const int b = blockIdx.x, c = threadIdx.x;
    v[c] = prompt[b * 512 + c];
    __syncthreads();
    const float mv = v[c];
    int rank = 0;
    for (int j = 0; j < 512; ++j) {
        float o = v[j];
        rank += (o > mv) || (o == mv && j < c);
    }
    sel[c] = (rank < 256) ? 1 : 0;
    __syncthreads();
    if (rank < 256) {
        int pos = 0;
        for (int j = 0; j < c; ++j) pos += sel[j];
        idx[b * 256 + pos] = c;
    }
}

// gather stacked wqkv rows (scale folded in!) and wo columns per top-k list
__global__ void k_gather(const int* __restrict__ idx, const float* __restrict__ ss,
                         const float* __restrict__ wq, const float* __restrict__ wk,
                         const float* __restrict__ wv, const float* __restrict__ wo,
                         bf16* __restrict__ wqkv_g, bf16* __restrict__ wo_g)
{
    const int b = blockIdx.z;
    const int* id = idx + b * 256;
    const int tid = blockIdx.x * 256 + threadIdx.x;  // < 393216
    {
        const int mat = tid >> 17, r = tid & 131071;
        const int j = r >> 9, c = r & 511;
        const int ch = id[j];
        const float* W = mat == 0 ? wq : (mat == 1 ? wk : wv);
        wqkv_g[(size_t)b * 393216 + tid] = f2b(W[ch * 512 + c] * (1.f + ss[b * 1024 + c]));
    }
    if (tid < 131072) {
        const int o = tid >> 8, j = tid & 255;
        wo_g[(size_t)b * 131072 + tid] = f2b(wo[o * 512 + id[j]]);
    }
}

// bqkv[b][j3] = B[id[j]] + sum_c W[id[j]][c] * shift[b][c]   (modulation fold)
__global__ void k_biasadj(const int* __restrict__ idx, const float* __restrict__ ss,
                          const float* __restrict__ wq, const float* __restrict__ bq,
                          const float* __restrict__ wk, const float* __restrict__ bk,
                          const float* __restrict__ wv, const float* __restrict__ bv,
                          float* __restrict__ bqkv)
{
    const int gw = (blockIdx.x * 256 + threadIdx.x) >> 6;
    const int lane = threadIdx.x & 63;
    if (gw >= 8 * 768) return;
    const int b = gw / 768, j3 = gw - b * 768;
    const int mat = j3 >> 8, j = j3 & 255;
    const int ch = idx[b * 256 + j];
    const float* W  = mat == 0 ? wq : (mat == 1 ? wk : wv);
    const float* Bb = mat == 0 ? bq : (mat == 1 ? bk : bv);
    const float* shift = ss + b * 1024 + 512;
    float s = 0.f;
    for (int c = lane; c < 512; c += 64)
        s += W[(size_t)ch * 512 + c] * shift[c];
    for (int off = 32; off; off >>= 1) s += __shfl_down(s, off);
    if (lane == 0) bqkv[b * 768 + j3] = Bb[ch] + s;
}

// reduce 8 fp32 split-K partials, softmax row (scale 1/16 = 256^-0.5), write P^T
__global__ void k_softmax_red(const float* __restrict__ part, bf16* __restrict__ Pt)
{
    const int row = blockIdx.x;          // b*256 + j
    const int b = row >> 8, j = row & 255;
    const int t = threadIdx.x;
    const int lane = t & 63, wv = t >> 6;
    __shared__ float redm[4], reds[4];
    float v = 0.f;
#pragma unroll
    for (int s = 0; s < 8; ++s)
        v += part[((size_t)(s * 8 + b) * 256 + j) * 256 + t];
    v *= 0.0625f;
    float m = v;
    for (int off = 32; off; off >>= 1) m = fmaxf(m, __shfl_down(m, off));
    if (lane == 0) redm[wv] = m;
    __syncthreads();
    m = fmaxf(fmaxf(redm[0], redm[1]), fmaxf(redm[2], redm[3]));
    const float e = __expf(v - m);
    float s = e;
    for (int off = 32; off; off >>= 1) s += __shfl_down(s, off);
    if (lane == 0) reds[wv] = s;
    __syncthreads();
    s = reds[0] + reds[1] + reds[2] + reds[3];
    Pt[(size_t)b * 65536 + (size_t)t * 256 + j] = f2b(e / s);  // P^T
}

// ---------------------------------------------------------------------------

extern "C" void kernel_launch(void* const* d_in, const int* in_sizes, int n_in,
                              void* d_out, int out_size, void* d_ws, size_t ws_size,
                              hipStream_t stream)
{
    const float* x        = (const float*)d_in[0];
    const float* temb     = (const float*)d_in[1];
    const float* w_affine = (const float*)d_in[2];
    const float* b_affine = (const float*)d_in[3];
    const float* w_tp     = (const float*)d_in[4];
    const float* b_tp     = (const float*)d_in[5];
    const float* w_m1     = (const float*)d_in[6];
    const float* b_m1     = (const float*)d_in[7];
    const float* w_m2     = (const float*)d_in[8];
    const float* b_m2     = (const float*)d_in[9];
    const float* wq       = (const float*)d_in[10];
    const float* bq       = (const float*)d_in[11];
    const float* wk       = (const float*)d_in[12];
    const float* bk       = (const float*)d_in[13];
    const float* wv       = (const float*)d_in[14];
    const float* bv       = (const float*)d_in[15];
    const float* wo       = (const float*)d_in[16];
    const float* bo       = (const float*)d_in[17];
    float* out = (float*)d_out;

    char* ws = (char*)d_ws;
    size_t off = 0;
    auto alloc = [&](size_t bytes) -> char* {
        char* p = ws + off;
        off += (bytes + 255) & ~(size_t)255;
        return p;
    };

    float* temb_act = (float*)alloc(4096 * 4);
    float* ssb      = (float*)alloc(8192 * 4);
    float* tp       = (float*)alloc(4096 * 4);
    float* xsump    = (float*)alloc((size_t)8 * 4096 * 4);
    float* hidden   = (float*)alloc(8192 * 4);
    float* prompt   = (float*)alloc(4096 * 4);
    int*   idx      = (int*)alloc(2048 * 4);
    bf16*  xT     = (bf16*)alloc((size_t)8 * 4096 * 512 * 2);
    float* part   = (float*)alloc((size_t)8 * 8 * 256 * 256 * 4);  // split-K partials
    bf16*  wqkv_g = (bf16*)alloc((size_t)8 * 768 * 512 * 2);
    float* bqkv_g = (float*)alloc(8 * 768 * 4);
    bf16*  wo_g   = (bf16*)alloc((size_t)8 * 512 * 256 * 2);
    bf16*  qb     = (bf16*)alloc((size_t)8 * 256 * 4096 * 2);
    bf16*  kb     = (bf16*)alloc((size_t)8 * 256 * 4096 * 2);
    bf16*  vT     = (bf16*)alloc((size_t)8 * 4096 * 256 * 2);
    bf16*  Pt     = (bf16*)alloc((size_t)8 * 256 * 256 * 2);
    bf16*  W2     = (bf16*)alloc((size_t)8 * 512 * 256 * 2);
    (void)ws_size; (void)n_in; (void)in_sizes; (void)out_size;

    // x transpose->bf16 + channel sums (only needs x)
    k_prep<<<dim3(8, 8, 8), 256, 0, stream>>>(x, xT, xsump);
    k_silu<<<16, 256, 0, stream>>>(temb, temb_act, 4096);
    k_smallgemm<<<2048, 256, 0, stream>>>(temb_act, w_affine, b_affine, ssb, 8, 1024, 512, 0);
    k_smallgemm<<<1024, 256, 0, stream>>>(temb_act, w_tp, b_tp, tp, 8, 512, 512, 0);
    k_mlp1<<<2048, 256, 0, stream>>>(ssb, xsump, tp, w_m1, b_m1, hidden);
    k_smallgemm<<<1024, 256, 0, stream>>>(hidden, w_m2, b_m2, prompt, 8, 512, 1024, 0);
    k_topk<<<8, 512, 0, stream>>>(prompt, idx);
    k_gather<<<dim3(1536, 1, 8), 256, 0, stream>>>(idx, ssb, wq, wk, wv, wo, wqkv_g, wo_g);
    k_biasadj<<<1536, 256, 0, stream>>>(idx, ssb, wq, bq, wk, bk, wv, bv, bqkv_g);
    // QKV from pre-transposed x, modulation folded into A/bias
    gemm_qkv2<<<dim3(6, 32, 8), 256, 0, stream>>>(wqkv_g, xT, bqkv_g, qb, kb, vT);
    // S split-K (8 chunks of 512)
    gemm_s_splitk<<<dim3(4, 2, 64), 256, 0, stream>>>(qb, kb, part);
    // softmax + split reduction -> P^T
    k_softmax_red<<<2048, 256, 0, stream>>>(part, Pt);
    // W2 = wo_g @ P  (512x256, K=256)
    gemm_bt<bf16><<<dim3(4, 4, 8), 256, 0, stream>>>(wo_g, 131072, Pt, 65536,
                                                     nullptr, 0, 0,
                                                     W2, 131072, 512, 256, 256, 0);
    // out = W2 @ v + bo  (512x4096, K=256)
    gemm_bt<float><<<dim3(64, 4, 8), 256, 0, stream>>>(W2, 131072, vT, 1048576,
                                                       bo, 0, 1,
                                                       out, 2097152, 512, 4096, 256, 0);
}

// Round 2
// 339.907 us; speedup vs baseline: 1.0327x; 1.0327x over previous
//
#include <hip/hip_runtime.h>
#include <hip/hip_bf16.h>
#include <math.h>

typedef __hip_bfloat16 bf16;
typedef __bf16 bf16x8 __attribute__((ext_vector_type(8)));
typedef float f32x4 __attribute__((ext_vector_type(4)));

static __device__ __forceinline__ float b2f(bf16 v) { return __bfloat162float(v); }
static __device__ __forceinline__ bf16 f2b(float v) { return __float2bfloat16(v); }

// async global->LDS, 16B per lane; LDS dest = wave-uniform base + lane*16
#define GLOAD16(g, l) __builtin_amdgcn_global_load_lds( \
    (const __attribute__((address_space(1))) void*)(g), \
    (__attribute__((address_space(3))) void*)(l), 16, 0, 0)

// ---------------------------------------------------------------------------
// Generic MFMA GEMM:  D[m][n] = sum_k A[m][k] * Bt[n][k]  (+ bias[m])
// Tile 128(M) x 64(N), BK=32, m97-style staging: linear LDS + global_load_lds.
// 1-D grid of NXB*NYB*8 blocks, XCD-swizzled: batch = id&7 pins one batch
// per XCD so the per-XCD L2 holds that batch's operands.
// ---------------------------------------------------------------------------
#define TM 128
#define TN 64
#define TK 32

template <typename TOUT>
__global__ __launch_bounds__(256) void gemm_bt(
    const bf16* __restrict__ A, size_t sA,
    const bf16* __restrict__ Bt, size_t sB,
    const float* __restrict__ bias, size_t sBias, int hasBias,
    TOUT* __restrict__ D, size_t sD,
    int M, int N, int Kd, int transStore, int NXB)
{
    const int id = blockIdx.x;
    const int bz = id & 7;          // batch -> XCD pin
    const int slot = id >> 3;
    const int bx = slot % NXB, by = slot / NXB;

    A  += (size_t)bz * sA;
    Bt += (size_t)bz * sB;
    D  += (size_t)bz * sD;
    if (hasBias) bias += (size_t)bz * sBias;

    const int m0 = by * TM, n0 = bx * TN;
    const int t = threadIdx.x, wv = t >> 6, lane = t & 63;
    const int lr = lane & 15, quad = lane >> 4;

    __shared__ bf16 lA[TM * TK];
    __shared__ bf16 lB[TN * TK];

    f32x4 acc[2][4];
#pragma unroll
    for (int i = 0; i < 2; ++i)
#pragma unroll
        for (int j = 0; j < 4; ++j) acc[i][j] = (f32x4){0.f, 0.f, 0.f, 0.f};

    // staging: wave wv covers rows [wv*16, wv*16+16) (+64 for A's 2nd half)
    const int srow = lane >> 2, scol = (lane & 3) * 8;
    const bf16* as0 = A  + (size_t)(m0 + wv * 16 + srow) * Kd + scol;
    const bf16* bs0 = Bt + (size_t)(n0 + wv * 16 + srow) * Kd + scol;
    bf16* la0 = lA + wv * 512;
    bf16* lb0 = lB + wv * 512;

    for (int k0 = 0; k0 < Kd; k0 += TK) {
        __syncthreads();
        GLOAD16(as0 + k0, la0);
        GLOAD16(as0 + (size_t)64 * Kd + k0, la0 + 2048);
        GLOAD16(bs0 + k0, lb0);
        __syncthreads();

        bf16x8 af0 = *(const bf16x8*)(lA + (wv * 32 + lr) * 32 + quad * 8);
        bf16x8 af1 = *(const bf16x8*)(lA + (wv * 32 + 16 + lr) * 32 + quad * 8);
#pragma unroll
        for (int j = 0; j < 4; ++j) {
            bf16x8 bfj = *(const bf16x8*)(lB + (j * 16 + lr) * 32 + quad * 8);
            acc[0][j] = __builtin_amdgcn_mfma_f32_16x16x32_bf16(af0, bfj, acc[0][j], 0, 0, 0);
            acc[1][j] = __builtin_amdgcn_mfma_f32_16x16x32_bf16(af1, bfj, acc[1][j], 0, 0, 0);
        }
    }

#pragma unroll
    for (int i = 0; i < 2; ++i) {
        const int mb = m0 + wv * 32 + i * 16 + quad * 4;
#pragma unroll
        for (int r = 0; r < 4; ++r) {
            const int mm = mb + r;
            const float bvv = hasBias ? bias[mm] : 0.f;
#pragma unroll
            for (int j = 0; j < 4; ++j) {
                const int nn = n0 + j * 16 + lr;
                const float v = acc[i][j][r] + bvv;
                const size_t o = transStore ? ((size_t)nn * M + mm)
                                            : ((size_t)mm * N + nn);
                if constexpr (__is_same(TOUT, float)) D[o] = v;
                else                                  D[o] = f2b(v);
            }
        }
    }
}

// ---------------------------------------------------------------------------
// x prep: x[b][512][4096] f32 -> xT[b][4096][512] bf16 (transpose+cast),
// fused per-channel partial sums xsump[8][b*512+c] (for the GAP branch).
// Grid (8 n-chunks of 512, 8 c-chunks of 64, 8 batches), 256 thr.
// Streaming (no reuse) -> no XCD swizzle needed.
// ---------------------------------------------------------------------------
__global__ __launch_bounds__(256) void k_prep(const float* __restrict__ x,
                                              bf16* __restrict__ xT,
                                              float* __restrict__ xsump)
{
    const int b = blockIdx.z;
    const int c0 = blockIdx.y * 64;
    const int n0 = blockIdx.x * 512;
    const int t = threadIdx.x;
    const int cr = t >> 2;        // 0..63
    const int sub = t & 3;        // 0..3
    __shared__ bf16 tile[64][72];

    const float* xrow = x + ((size_t)b * 512 + c0 + cr) * 4096 + n0 + sub * 16;
    float s = 0.f;

    for (int st = 0; st < 8; ++st) {
        __syncthreads();
        float4 f[4];
#pragma unroll
        for (int q = 0; q < 4; ++q) f[q] = *(const float4*)(xrow + st * 64 + q * 4);
#pragma unroll
        for (int q = 0; q < 4; ++q) {
            s += f[q].x + f[q].y + f[q].z + f[q].w;
            union { bf16 h[4]; uint2 u; } p;
            p.h[0] = f2b(f[q].x); p.h[1] = f2b(f[q].y);
            p.h[2] = f2b(f[q].z); p.h[3] = f2b(f[q].w);
            *(uint2*)&tile[cr][sub * 16 + q * 4] = p.u;
        }
        __syncthreads();
        union { bf16 h[8]; uint4 u; } o0, o1;
#pragma unroll
        for (int i = 0; i < 8; ++i) o0.h[i] = tile[sub * 16 + i][cr];
#pragma unroll
        for (int i = 0; i < 8; ++i) o1.h[i] = tile[sub * 16 + 8 + i][cr];
        bf16* orow = xT + ((size_t)b * 4096 + n0 + st * 64 + cr) * 512 + c0 + sub * 16;
        *(uint4*)(orow)     = o0.u;
        *(uint4*)(orow + 8) = o1.u;
    }
    s += __shfl_down(s, 2);
    s += __shfl_down(s, 1);
    if (sub == 0) xsump[(size_t)blockIdx.x * 4096 + b * 512 + c0 + cr] = s;
}

// ---------------------------------------------------------------------------
// QKV GEMM with modulation folded into weights:
//   q/k/v = (Wg*(1+scale)) @ x + (b + Wg@shift)
// A = wqkv_g [b][768][512] bf16 (scale pre-folded), Bt = xT [b][4096][512].
// 1-D grid 1536 blocks, XCD-swizzled: batch = id&7 (one batch per XCD:
// per-XCD unique = A 0.79MB + B 4MB; concurrent slice ~2MB -> L2-resident).
// Within a batch: m-tile fastest (6 m-tiles share each B n-tile).
// q,k natural [b][256][4096]; v transposed [b][4096][256].
// ---------------------------------------------------------------------------
__global__ __launch_bounds__(256) void gemm_qkv2(
    const bf16* __restrict__ Aall, const bf16* __restrict__ xT,
    const float* __restrict__ bias,
    bf16* __restrict__ qb, bf16* __restrict__ kb, bf16* __restrict__ vT)
{
    const int id = blockIdx.x;
    const int b = id & 7;               // batch -> XCD pin
    const int slot = id >> 3;           // 0..191
    const int mt = slot % 6;            // m-tile fastest
    const int n0 = (slot / 6) * 128;

    const bf16* A  = Aall + (size_t)b * 393216 + (size_t)mt * 65536;
    const bf16* Bt = xT + (size_t)b * 2097152;
    bias += b * 768 + mt * 128;

    const int t = threadIdx.x, w = t >> 6, lane = t & 63;
    const int lr = lane & 15, quad = lane >> 4;
    const int wr = w >> 1, wc = w & 1;

    __shared__ bf16 lA[128 * 32];
    __shared__ bf16 lB[128 * 32];

    f32x4 acc[4][4];
#pragma unroll
    for (int i = 0; i < 4; ++i)
#pragma unroll
        for (int j = 0; j < 4; ++j) acc[i][j] = (f32x4){0.f, 0.f, 0.f, 0.f};

    const int srow = lane >> 2, scol = (lane & 3) * 8;
    const bf16* as0 = A  + (size_t)(w * 16 + srow) * 512 + scol;
    const bf16* bs0 = Bt + (size_t)(n0 + w * 16 + srow) * 512 + scol;
    bf16* la0 = lA + w * 512;
    bf16* lb0 = lB + w * 512;

    for (int k0 = 0; k0 < 512; k0 += 32) {
        __syncthreads();
        GLOAD16(as0 + k0, la0);
        GLOAD16(as0 + 32768 + k0, la0 + 2048);   // +64 rows * 512
        GLOAD16(bs0 + k0, lb0);
        GLOAD16(bs0 + 32768 + k0, lb0 + 2048);
        __syncthreads();

        bf16x8 af[4], bfr[4];
#pragma unroll
        for (int i = 0; i < 4; ++i)
            af[i] = *(const bf16x8*)(lA + (wr * 64 + i * 16 + lr) * 32 + quad * 8);
#pragma unroll
        for (int j = 0; j < 4; ++j)
            bfr[j] = *(const bf16x8*)(lB + (wc * 64 + j * 16 + lr) * 32 + quad * 8);
#pragma unroll
        for (int i = 0; i < 4; ++i)
#pragma unroll
            for (int j = 0; j < 4; ++j)
                acc[i][j] = __builtin_amdgcn_mfma_f32_16x16x32_bf16(af[i], bfr[j], acc[i][j], 0, 0, 0);
    }

#pragma unroll
    for (int i = 0; i < 4; ++i) {
        const int mq = wr * 64 + i * 16 + quad * 4;
#pragma unroll
        for (int r = 0; r < 4; ++r) {
            const int ml = mq + r;                 // 0..127 in tile
            const float bvv = bias[ml];
            const int mmg = mt * 128 + ml;         // 0..767
            const int mloc = mmg & 255;
#pragma unroll
            for (int j = 0; j < 4; ++j) {
                const int nn = n0 + wc * 64 + j * 16 + lr;
                const float v = acc[i][j][r] + bvv;
                if (mmg < 256)      qb[(size_t)b * 1048576 + (size_t)mloc * 4096 + nn] = f2b(v);
                else if (mmg < 512) kb[(size_t)b * 1048576 + (size_t)mloc * 4096 + nn] = f2b(v);
                else                vT[(size_t)b * 1048576 + (size_t)nn * 256 + mloc] = f2b(v);
            }
        }
    }
}

// ---------------------------------------------------------------------------
// Split-K S-GEMM: part[s][b][m][n] = sum_{k in chunk s} q[b][m][k]*k[b][n][k]
// 8 splits of 512; 1-D grid 512 blocks, XCD-swizzled (batch = id&7:
// per-XCD unique = q 2MB + k 2MB -> L2-resident).
// ---------------------------------------------------------------------------
__global__ __launch_bounds__(256) void gemm_s_splitk(
    const bf16* __restrict__ qb, const bf16* __restrict__ kb,
    float* __restrict__ part)
{
    const int id = blockIdx.x;
    const int b = id & 7;               // batch -> XCD pin
    const int slot = id >> 3;           // 0..63
    const int s = slot >> 3;            // split 0..7
    const int rem = slot & 7;
    const int m0 = (rem >> 2) * TM, n0 = (rem & 3) * TN;

    const bf16* A  = qb + (size_t)b * 1048576;
    const bf16* Bt = kb + (size_t)b * 1048576;

    const int t = threadIdx.x, wv = t >> 6, lane = t & 63;
    const int lr = lane & 15, quad = lane >> 4;

    __shared__ bf16 lA[TM * TK];
    __shared__ bf16 lB[TN * TK];

    f32x4 acc[2][4];
#pragma unroll
    for (int i = 0; i < 2; ++i)
#pragma unroll
        for (int j = 0; j < 4; ++j) acc[i][j] = (f32x4){0.f, 0.f, 0.f, 0.f};

    const int srow = lane >> 2, scol = (lane & 3) * 8;
    const bf16* as0 = A  + (size_t)(m0 + wv * 16 + srow) * 4096 + scol;
    const bf16* bs0 = Bt + (size_t)(n0 + wv * 16 + srow) * 4096 + scol;
    bf16* la0 = lA + wv * 512;
    bf16* lb0 = lB + wv * 512;

    const int kBeg = s * 512, kEnd = kBeg + 512;
    for (int k0 = kBeg; k0 < kEnd; k0 += TK) {
        __syncthreads();
        GLOAD16(as0 + k0, la0);
        GLOAD16(as0 + (size_t)64 * 4096 + k0, la0 + 2048);
        GLOAD16(bs0 + k0, lb0);
        __syncthreads();

        bf16x8 af0 = *(const bf16x8*)(lA + (wv * 32 + lr) * 32 + quad * 8);
        bf16x8 af1 = *(const bf16x8*)(lA + (wv * 32 + 16 + lr) * 32 + quad * 8);
#pragma unroll
        for (int j = 0; j < 4; ++j) {
            bf16x8 bfj = *(const bf16x8*)(lB + (j * 16 + lr) * 32 + quad * 8);
            acc[0][j] = __builtin_amdgcn_mfma_f32_16x16x32_bf16(af0, bfj, acc[0][j], 0, 0, 0);
            acc[1][j] = __builtin_amdgcn_mfma_f32_16x16x32_bf16(af1, bfj, acc[1][j], 0, 0, 0);
        }
    }

    float* dst = part + ((size_t)(s * 8 + b) * 256) * 256;
#pragma unroll
    for (int i = 0; i < 2; ++i) {
        const int mb = m0 + wv * 32 + i * 16 + quad * 4;
#pragma unroll
        for (int r = 0; r < 4; ++r) {
            const int mm = mb + r;
#pragma unroll
            for (int j = 0; j < 4; ++j)
                dst[(size_t)mm * 256 + n0 + j * 16 + lr] = acc[i][j][r];
        }
    }
}

// ---------------------------------------------------------------------------
// Small kernels
// ---------------------------------------------------------------------------

__global__ void k_silu(const float* __restrict__ in, float* __restrict__ out, int n)
{
    int i = blockIdx.x * 256 + threadIdx.x;
    if (i < n) {
        float v = in[i];
        out[i] = v / (1.f + expf(-v));
    }
}

__global__ void k_smallgemm(const float* __restrict__ in, const float* __restrict__ W,
                            const float* __restrict__ bias, float* __restrict__ out,
                            int Mrows, int O, int Kd, int act)
{
    const int gw = (blockIdx.x * 256 + threadIdx.x) >> 6;
    const int lane = threadIdx.x & 63;
    if (gw >= Mrows * O) return;
    const int m = gw / O, o = gw - m * O;
    float s = 0.f;
    for (int k = lane; k < Kd; k += 64)
        s += in[m * Kd + k] * W[(size_t)o * Kd + k];
    for (int off = 32; off; off >>= 1) s += __shfl_down(s, off);
    if (lane == 0) {
        s += bias[o];
        if (act) s = s / (1.f + expf(-s));
        out[m * O + o] = s;
    }
}

// hidden[m][o] = silu(pm @ w_m1^T + b_m1); pm from ss / xsump(sum of 8, /4096) / tp
__global__ void k_mlp1(const float* __restrict__ ss, const float* __restrict__ xsump,
                       const float* __restrict__ tp, const float* __restrict__ w_m1,
                       const float* __restrict__ b_m1, float* __restrict__ hidden)
{
    const int gw = (blockIdx.x * 256 + threadIdx.x) >> 6;
    const int lane = threadIdx.x & 63;
    if (gw >= 8 * 1024) return;
    const int m = gw >> 10, o = gw & 1023;
    float s = 0.f;
    for (int k = lane; k < 1024; k += 64) {
        float pv;
        if (k < 512) {
            float xs = 0.f;
#pragma unroll
            for (int p = 0; p < 8; ++p) xs += xsump[p * 4096 + m * 512 + k];
            pv = (1.f + ss[m * 1024 + k]) * (xs * (1.f / 4096.f))
                 + ss[m * 1024 + 512 + k];
        } else {
            pv = tp[m * 512 + k - 512];
        }
        s += pv * w_m1[(size_t)o * 1024 + k];
    }
    for (int off = 32; off; off >>= 1) s += __shfl_down(s, off);
    if (lane == 0) {
        s += b_m1[o];
        hidden[m * 1024 + o] = s / (1.f + expf(-s));
    }
}

// top-256 set (order-free downstream; rank tie-break by lower index)
__global__ void k_topk(const float* __restrict__ prompt, int* __restrict__ idx)
{
    __shared__ float v[512];
    __shared__ int sel[512];
    const int b = blockIdx.x, c = threadIdx.x;
    v[c] = prompt[b * 512 + c];
    __syncthreads();
    const float mv = v[c];
    int rank = 0;
    for (int j = 0; j < 512; ++j) {
        float o = v[j];
        rank += (o > mv) || (o == mv && j < c);
    }
    sel[c] = (rank < 256) ? 1 : 0;
    __syncthreads();
    if (rank < 256) {
        int pos = 0;
        for (int j = 0; j < c; ++j) pos += sel[j];
        idx[b * 256 + pos] = c;
    }
}

// gather stacked wqkv rows (scale folded in!) and wo columns per top-k list
__global__ void k_gather(const int* __restrict__ idx, const float* __restrict__ ss,
                         const float* __restrict__ wq, const float* __restrict__ wk,
                         const float* __restrict__ wv, const float* __restrict__ wo,
                         bf16* __restrict__ wqkv_g, bf16* __restrict__ wo_g)
{
    const int b = blockIdx.z;
    const int* id = idx + b * 256;
    const int tid = blockIdx.x * 256 + threadIdx.x;  // < 393216
    {
        const int mat = tid >> 17, r = tid & 131071;
        const int j = r >> 9, c = r & 511;
        const int ch = id[j];
        const float* W = mat == 0 ? wq : (mat == 1 ? wk : wv);
        wqkv_g[(size_t)b * 393216 + tid] = f2b(W[ch * 512 + c] * (1.f + ss[b * 1024 + c]));
    }
    if (tid < 131072) {
        const int o = tid >> 8, j = tid & 255;
        wo_g[(size_t)b * 131072 + tid] = f2b(wo[o * 512 + id[j]]);
    }
}

// bqkv[b][j3] = B[id[j]] + sum_c W[id[j]][c] * shift[b][c]   (modulation fold)
__global__ void k_biasadj(const int* __restrict__ idx, const float* __restrict__ ss,
                          const float* __restrict__ wq, const float* __restrict__ bq,
                          const float* __restrict__ wk, const float* __restrict__ bk,
                          const float* __restrict__ wv, const float* __restrict__ bv,
                          float* __restrict__ bqkv)
{
    const int gw = (blockIdx.x * 256 + threadIdx.x) >> 6;
    const int lane = threadIdx.x & 63;
    if (gw >= 8 * 768) return;
    const int b = gw / 768, j3 = gw - b * 768;
    const int mat = j3 >> 8, j = j3 & 255;
    const int ch = idx[b * 256 + j];
    const float* W  = mat == 0 ? wq : (mat == 1 ? wk : wv);
    const float* Bb = mat == 0 ? bq : (mat == 1 ? bk : bv);
    const float* shift = ss + b * 1024 + 512;
    float s = 0.f;
    for (int c = lane; c < 512; c += 64)
        s += W[(size_t)ch * 512 + c] * shift[c];
    for (int off = 32; off; off >>= 1) s += __shfl_down(s, off);
    if (lane == 0) bqkv[b * 768 + j3] = Bb[ch] + s;
}

// reduce 8 fp32 split-K partials, softmax row (scale 1/16 = 256^-0.5), write P^T
__global__ void k_softmax_red(const float* __restrict__ part, bf16* __restrict__ Pt)
{
    const int row = blockIdx.x;          // b*256 + j
    const int b = row >> 8, j = row & 255;
    const int t = threadIdx.x;
    const int lane = t & 63, wv = t >> 6;
    __shared__ float redm[4], reds[4];
    float v = 0.f;
#pragma unroll
    for (int s = 0; s < 8; ++s)
        v += part[((size_t)(s * 8 + b) * 256 + j) * 256 + t];
    v *= 0.0625f;
    float m = v;
    for (int off = 32; off; off >>= 1) m = fmaxf(m, __shfl_down(m, off));
    if (lane == 0) redm[wv] = m;
    __syncthreads();
    m = fmaxf(fmaxf(redm[0], redm[1]), fmaxf(redm[2], redm[3]));
    const float e = __expf(v - m);
    float s = e;
    for (int off = 32; off; off >>= 1) s += __shfl_down(s, off);
    if (lane == 0) reds[wv] = s;
    __syncthreads();
    s = reds[0] + reds[1] + reds[2] + reds[3];
    Pt[(size_t)b * 65536 + (size_t)t * 256 + j] = f2b(e / s);  // P^T
}

// ---------------------------------------------------------------------------

extern "C" void kernel_launch(void* const* d_in, const int* in_sizes, int n_in,
                              void* d_out, int out_size, void* d_ws, size_t ws_size,
                              hipStream_t stream)
{
    const float* x        = (const float*)d_in[0];
    const float* temb     = (const float*)d_in[1];
    const float* w_affine = (const float*)d_in[2];
    const float* b_affine = (const float*)d_in[3];
    const float* w_tp     = (const float*)d_in[4];
    const float* b_tp     = (const float*)d_in[5];
    const float* w_m1     = (const float*)d_in[6];
    const float* b_m1     = (const float*)d_in[7];
    const float* w_m2     = (const float*)d_in[8];
    const float* b_m2     = (const float*)d_in[9];
    const float* wq       = (const float*)d_in[10];
    const float* bq       = (const float*)d_in[11];
    const float* wk       = (const float*)d_in[12];
    const float* bk       = (const float*)d_in[13];
    const float* wv       = (const float*)d_in[14];
    const float* bv       = (const float*)d_in[15];
    const float* wo       = (const float*)d_in[16];
    const float* bo       = (const float*)d_in[17];
    float* out = (float*)d_out;

    char* ws = (char*)d_ws;
    size_t off = 0;
    auto alloc = [&](size_t bytes) -> char* {
        char* p = ws + off;
        off += (bytes + 255) & ~(size_t)255;
        return p;
    };

    float* temb_act = (float*)alloc(4096 * 4);
    float* ssb      = (float*)alloc(8192 * 4);
    float* tp       = (float*)alloc(4096 * 4);
    float* xsump    = (float*)alloc((size_t)8 * 4096 * 4);
    float* hidden   = (float*)alloc(8192 * 4);
    float* prompt   = (float*)alloc(4096 * 4);
    int*   idx      = (int*)alloc(2048 * 4);
    bf16*  xT     = (bf16*)alloc((size_t)8 * 4096 * 512 * 2);
    float* part   = (float*)alloc((size_t)8 * 8 * 256 * 256 * 4);  // split-K partials
    bf16*  wqkv_g = (bf16*)alloc((size_t)8 * 768 * 512 * 2);
    float* bqkv_g = (float*)alloc(8 * 768 * 4);
    bf16*  wo_g   = (bf16*)alloc((size_t)8 * 512 * 256 * 2);
    bf16*  qb     = (bf16*)alloc((size_t)8 * 256 * 4096 * 2);
    bf16*  kb     = (bf16*)alloc((size_t)8 * 256 * 4096 * 2);
    bf16*  vT     = (bf16*)alloc((size_t)8 * 4096 * 256 * 2);
    bf16*  Pt     = (bf16*)alloc((size_t)8 * 256 * 256 * 2);
    bf16*  W2     = (bf16*)alloc((size_t)8 * 512 * 256 * 2);
    (void)ws_size; (void)n_in; (void)in_sizes; (void)out_size;

    // x transpose->bf16 + channel sums (only needs x)
    k_prep<<<dim3(8, 8, 8), 256, 0, stream>>>(x, xT, xsump);
    k_silu<<<16, 256, 0, stream>>>(temb, temb_act, 4096);
    k_smallgemm<<<2048, 256, 0, stream>>>(temb_act, w_affine, b_affine, ssb, 8, 1024, 512, 0);
    k_smallgemm<<<1024, 256, 0, stream>>>(temb_act, w_tp, b_tp, tp, 8, 512, 512, 0);
    k_mlp1<<<2048, 256, 0, stream>>>(ssb, xsump, tp, w_m1, b_m1, hidden);
    k_smallgemm<<<1024, 256, 0, stream>>>(hidden, w_m2, b_m2, prompt, 8, 512, 1024, 0);
    k_topk<<<8, 512, 0, stream>>>(prompt, idx);
    k_gather<<<dim3(1536, 1, 8), 256, 0, stream>>>(idx, ssb, wq, wk, wv, wo, wqkv_g, wo_g);
    k_biasadj<<<1536, 256, 0, stream>>>(idx, ssb, wq, bq, wk, bk, wv, bv, bqkv_g);
    // QKV from pre-transposed x, modulation folded into A/bias (XCD-swizzled)
    gemm_qkv2<<<1536, 256, 0, stream>>>(wqkv_g, xT, bqkv_g, qb, kb, vT);
    // S split-K (8 chunks of 512, XCD-swizzled)
    gemm_s_splitk<<<512, 256, 0, stream>>>(qb, kb, part);
    // softmax + split reduction -> P^T
    k_softmax_red<<<2048, 256, 0, stream>>>(part, Pt);
    // W2 = wo_g @ P  (512x256, K=256)
    gemm_bt<bf16><<<128, 256, 0, stream>>>(wo_g, 131072, Pt, 65536,
                                           nullptr, 0, 0,
                                           W2, 131072, 512, 256, 256, 0, 4);
    // out = W2 @ v + bo  (512x4096, K=256)
    gemm_bt<float><<<2048, 256, 0, stream>>>(W2, 131072, vT, 1048576,
                                             bo, 0, 1,
                                             out, 2097152, 512, 4096, 256, 0, 64);
}